// Round 5
// baseline (234.507 us; speedup 1.0000x reference)
//
#include <hip/hip_runtime.h>

#define NB    128
#define NT    8192
#define TPB   512
#define CHUNK 16
#define NRATE 4

// Raw gfx950 transcendentals: v_exp_f32 computes 2^x, v_log_f32 computes log2(x).
__device__ __forceinline__ float fexp2(float x) { return __builtin_amdgcn_exp2f(x); }
__device__ __forceinline__ float flog2(float x) { return __builtin_amdgcn_logf(x); }

// XOR swizzle on float index (involution within 256-float tiles; float4 groups
// stay contiguous & 16B aligned). Both staging patterns (write tid*16+4j, read
// wbase+k*256+lane*4) put 8 lanes on each 16B bank-group -> conflict-free.
__device__ __forceinline__ int swz(int n) { return n ^ (((n >> 5) & 7) << 2); }

// FUSED: one block per (b, f) row computes ALL 4 rates. 1024 blocks x 512 thr
// = 4 blocks/CU, one residency round. x is read ONCE (33.5 MB instead of the
// t-split's 134 MB of HBM+L3 reads); the 4 rates share one set of loads, one
// 4-wide shuffle scan, and ONE __syncthreads. Output staging is per-wave
// (intra-wave DS ordering -> no barriers, including across t iterations).
// t-loop pipelines: rate t+1's transcendentals overlap rate t's global stores.
__global__ __launch_bounds__(TPB, 8) void mrpcen_kernel(
    const float* __restrict__ x,
    const float* __restrict__ log_alpha,
    const float* __restrict__ log_delta,
    const float* __restrict__ log_r,
    float* __restrict__ out)
{
    __shared__ __align__(16) float sh[NT];   // 32 KiB: output staging slices
    __shared__ float4 sWagg[8];              // cross-wave scan aggregates (4 rates)

    const int tid  = threadIdx.x;
    const int lane = tid & 63;
    const int wid  = tid >> 6;

    const int bf = blockIdx.x;               // 0..1023
    const int b  = bf >> 7;
    const int f  = bf & (NB - 1);

    const float* xrow = x + (size_t)bf * NT;

    // per-band params (stored in log space)
    const float alpha  = __expf(log_alpha[f]);
    const float r      = __expf(log_r[f]);
    const float delta  = __expf(log_delta[f]);
    const float deltar = __expf(r * log_delta[f]);  // delta^r, exact from log param
    const float nalpha = -alpha;

    // rates t_vals = {2,8,32,128} = 2 << 2t; A[t] = (1-s)^16 via 4 squarings
    float s[NRATE], A[NRATE];
#pragma unroll
    for (int t = 0; t < NRATE; t++) {
        const float tt = (float)(2 << (2 * t));
        const float t2 = tt * tt;
        s[t] = (sqrtf(1.f + 4.f * t2) - 1.f) / (2.f * t2);
        float a = 1.f - s[t];
        a = a * a; a = a * a; a = a * a; a = a * a;
        A[t] = a;
    }

    // ---- 1. direct loads: lane's own 16 contiguous floats (R3==R4 proved
    //         this pattern costs nothing vs staged-coalesced) ----
    float xc[CHUNK];
#pragma unroll
    for (int j = 0; j < 4; j++) {
        float4 v4 = *reinterpret_cast<const float4*>(xrow + tid * CHUNK + 4 * j);
        xc[4 * j + 0] = v4.x; xc[4 * j + 1] = v4.y;
        xc[4 * j + 2] = v4.z; xc[4 * j + 3] = v4.w;
    }
    const float x0 = xrow[0];   // uniform -> scalar load; scan init m[-1] = x[0]

    // ---- 2. local affine compose, all 4 rates ----
    float v[NRATE] = {0.f, 0.f, 0.f, 0.f};
#pragma unroll
    for (int i = 0; i < CHUNK; i++) {
        const float xi = xc[i];
#pragma unroll
        for (int t = 0; t < NRATE; t++)
            v[t] = s[t] * xi + (1.f - s[t]) * v[t];
    }

    // ---- 3. in-wave 4-wide Kogge-Stone scan (shared shuffle steps) ----
    float ap[NRATE] = {A[0], A[1], A[2], A[3]};
#pragma unroll
    for (int d = 1; d < 64; d <<= 1) {
#pragma unroll
        for (int t = 0; t < NRATE; t++) {
            const float up = __shfl_up(v[t], d);
            if (lane >= d) v[t] += ap[t] * up;
            ap[t] *= ap[t];
        }
    }
    // ap[t] == A[t]^64 now
    if (lane == 63) sWagg[wid] = make_float4(v[0], v[1], v[2], v[3]);
    __syncthreads();                         // the ONLY block barrier

    // ---- 4. incoming state per rate ----
    float m_in[NRATE];
    {
        float pre[NRATE] = {0.f, 0.f, 0.f, 0.f};
#pragma unroll
        for (int k = 0; k < 7; k++) {
            if (wid > k) {                   // wave-uniform branch
                const float4 w4 = sWagg[k];
                pre[0] = ap[0] * pre[0] + w4.x;
                pre[1] = ap[1] * pre[1] + w4.y;
                pre[2] = ap[2] * pre[2] + w4.z;
                pre[3] = ap[3] * pre[3] + w4.w;
            }
        }
#pragma unroll
        for (int t = 0; t < NRATE; t++) {
            float pl = 1.f, base = A[t];     // A^lane, 6-bit binary powering
            int e = lane;
#pragma unroll
            for (int bit = 0; bit < 6; bit++) {
                if (e & 1) pl *= base;
                base *= base; e >>= 1;
            }
            float aw = 1.f, wb = ap[t];      // (A^64)^wid, 3-bit powering
            int ew = wid;
#pragma unroll
            for (int bit = 0; bit < 3; bit++) {
                if (ew & 1) aw *= wb;
                wb *= wb; ew >>= 1;
            }
            const float vprev = __shfl_up(v[t], 1);
            m_in[t] = pl * (aw * x0 + pre[t]) + ((lane > 0) ? vprev : 0.f);
        }
    }

    // ---- 5. per-rate epilogue: recurrence + PCEN, per-wave stage, store ----
    // No barriers: each wave touches only its own 1024-float slice of sh, and
    // DS ops from one wave execute in order (t+1 stage-writes cannot pass t's
    // stage-reads). Rate t+1's VALU/trans work overlaps rate t's global stores.
    const int wbase = wid << 10;
#pragma unroll
    for (int t = 0; t < NRATE; t++) {
        const float st = s[t], a1 = 1.f - s[t];
        float m = m_in[t];
#pragma unroll
        for (int j = 0; j < 4; j++) {
            float ov[4];
#pragma unroll
            for (int q = 0; q < 4; q++) {
                const float xi = xc[4 * j + q];
                m = st * xi + a1 * m;
                // smooth = (eps + m)^(-alpha);  exp2/log2 native
                const float smooth = fexp2(nalpha * flog2(1e-5f + m));
                // pcen = (x*smooth + delta)^r - delta^r   (arg >= delta > 0)
                ov[q] = fexp2(r * flog2(xi * smooth + delta)) - deltar;
            }
            *reinterpret_cast<float4*>(&sh[swz(tid * CHUNK + 4 * j)]) =
                make_float4(ov[0], ov[1], ov[2], ov[3]);
        }
        float* oplane = out + (((size_t)b * 4 + t) * NB + f) * (size_t)NT;
#pragma unroll
        for (int k = 0; k < 4; k++) {
            const int n = wbase + k * 256 + lane * 4;
            float4 o = *reinterpret_cast<const float4*>(&sh[swz(n)]);
            *reinterpret_cast<float4*>(oplane + n) = o;
        }
    }
}

extern "C" void kernel_launch(void* const* d_in, const int* in_sizes, int n_in,
                              void* d_out, int out_size, void* d_ws, size_t ws_size,
                              hipStream_t stream) {
    const float* x         = (const float*)d_in[0];
    const float* log_alpha = (const float*)d_in[1];
    const float* log_delta = (const float*)d_in[2];
    const float* log_r     = (const float*)d_in[3];
    float* out = (float*)d_out;

    // one block per (b, f) row: 8 * 128 = 1024 blocks, all 4 rates fused
    mrpcen_kernel<<<dim3(8 * NB), dim3(TPB), 0, stream>>>(
        x, log_alpha, log_delta, log_r, out);
}

// Round 6
// 163.978 us; speedup vs baseline: 1.4301x; 1.4301x over previous
//
#include <hip/hip_runtime.h>

#define NB    128
#define NT    8192
#define TPB   512
#define CHUNK 16
#define NRATE 4

// Raw gfx950 transcendentals: v_exp_f32 computes 2^x, v_log_f32 computes log2(x).
__device__ __forceinline__ float fexp2(float x) { return __builtin_amdgcn_exp2f(x); }
__device__ __forceinline__ float flog2(float x) { return __builtin_amdgcn_logf(x); }

// XOR swizzle on float index (involution within 256-float tiles; float4 groups
// stay contiguous & 16B aligned). Both staging patterns (write tid*16+4j, read
// wbase+k*256+lane*4) put 8 lanes on each 16B bank-group -> conflict-free.
__device__ __forceinline__ int swz(int n) { return n ^ (((n >> 5) & 7) << 2); }

// FUSED: one block per (b, f) row computes ALL 4 rates; x read once.
// __launch_bounds__(512, 4): 128-VGPR budget. The round-5 (512,8) variant
// capped VGPRs at 64 -> the 4-rate state spilled to scratch -> +189 MB of
// HBM writes (WRITE_SIZE 323 MB vs 134 ideal) and a 101 us kernel. 16
// waves/CU is ample TLP for a write-bound kernel; spill-freedom is worth 2x
// occupancy here.
__global__ __launch_bounds__(TPB, 4) void mrpcen_kernel(
    const float* __restrict__ x,
    const float* __restrict__ log_alpha,
    const float* __restrict__ log_delta,
    const float* __restrict__ log_r,
    float* __restrict__ out)
{
    __shared__ __align__(16) float sh[NT];   // 32 KiB: output staging slices
    __shared__ float4 sWagg[8];              // cross-wave scan aggregates (4 rates)

    const int tid  = threadIdx.x;
    const int lane = tid & 63;
    const int wid  = tid >> 6;

    const int bf = blockIdx.x;               // 0..1023
    const int b  = bf >> 7;
    const int f  = bf & (NB - 1);

    const float* xrow = x + (size_t)bf * NT;

    // per-band params (stored in log space)
    const float alpha  = __expf(log_alpha[f]);
    const float r      = __expf(log_r[f]);
    const float delta  = __expf(log_delta[f]);
    const float deltar = __expf(r * log_delta[f]);  // delta^r, exact from log param
    const float nalpha = -alpha;

    // rates t_vals = {2,8,32,128} = 2 << 2t; all literal inputs -> s[], A[]
    // constant-fold at compile time (no VGPR cost).
    float s[NRATE], A[NRATE];
#pragma unroll
    for (int t = 0; t < NRATE; t++) {
        const float tt = (float)(2 << (2 * t));
        const float t2 = tt * tt;
        s[t] = (sqrtf(1.f + 4.f * t2) - 1.f) / (2.f * t2);
        float a = 1.f - s[t];
        a = a * a; a = a * a; a = a * a; a = a * a;   // (1-s)^16
        A[t] = a;
    }

    // ---- 1. direct loads: lane's own 16 contiguous floats (R3==R4 proved
    //         this pattern costs nothing vs staged-coalesced) ----
    float xc[CHUNK];
#pragma unroll
    for (int j = 0; j < 4; j++) {
        float4 v4 = *reinterpret_cast<const float4*>(xrow + tid * CHUNK + 4 * j);
        xc[4 * j + 0] = v4.x; xc[4 * j + 1] = v4.y;
        xc[4 * j + 2] = v4.z; xc[4 * j + 3] = v4.w;
    }
    const float x0 = xrow[0];   // uniform -> scalar load; scan init m[-1] = x[0]

    // ---- 2. local affine compose, all 4 rates ----
    float v[NRATE] = {0.f, 0.f, 0.f, 0.f};
#pragma unroll
    for (int i = 0; i < CHUNK; i++) {
        const float xi = xc[i];
#pragma unroll
        for (int t = 0; t < NRATE; t++)
            v[t] = s[t] * xi + (1.f - s[t]) * v[t];
    }

    // ---- 3. in-wave 4-wide Kogge-Stone scan (shared shuffle steps) ----
    float ap[NRATE] = {A[0], A[1], A[2], A[3]};
#pragma unroll
    for (int d = 1; d < 64; d <<= 1) {
#pragma unroll
        for (int t = 0; t < NRATE; t++) {
            const float up = __shfl_up(v[t], d);
            if (lane >= d) v[t] += ap[t] * up;
            ap[t] *= ap[t];
        }
    }
    // ap[t] == A[t]^64 now
    if (lane == 63) sWagg[wid] = make_float4(v[0], v[1], v[2], v[3]);
    __syncthreads();                         // the ONLY block barrier

    // ---- 4. incoming state per rate ----
    float m_in[NRATE];
    {
        float pre[NRATE] = {0.f, 0.f, 0.f, 0.f};
#pragma unroll
        for (int k = 0; k < 7; k++) {
            if (wid > k) {                   // wave-uniform branch
                const float4 w4 = sWagg[k];
                pre[0] = ap[0] * pre[0] + w4.x;
                pre[1] = ap[1] * pre[1] + w4.y;
                pre[2] = ap[2] * pre[2] + w4.z;
                pre[3] = ap[3] * pre[3] + w4.w;
            }
        }
#pragma unroll
        for (int t = 0; t < NRATE; t++) {
            float pl = 1.f, base = A[t];     // A^lane, 6-bit binary powering
            int e = lane;
#pragma unroll
            for (int bit = 0; bit < 6; bit++) {
                if (e & 1) pl *= base;
                base *= base; e >>= 1;
            }
            float aw = 1.f, wb = ap[t];      // (A^64)^wid, 3-bit powering
            int ew = wid;
#pragma unroll
            for (int bit = 0; bit < 3; bit++) {
                if (ew & 1) aw *= wb;
                wb *= wb; ew >>= 1;
            }
            const float vprev = __shfl_up(v[t], 1);
            m_in[t] = pl * (aw * x0 + pre[t]) + ((lane > 0) ? vprev : 0.f);
        }
    }

    // ---- 5. per-rate epilogue: recurrence + PCEN, per-wave stage, store ----
    // No barriers: each wave touches only its own 1024-float slice of sh, and
    // DS ops from one wave execute in order (t+1 stage-writes cannot pass t's
    // stage-reads). Rate t+1's VALU/trans work overlaps rate t's global stores.
    const int wbase = wid << 10;
#pragma unroll
    for (int t = 0; t < NRATE; t++) {
        const float st = s[t], a1 = 1.f - s[t];
        float m = m_in[t];
#pragma unroll
        for (int j = 0; j < 4; j++) {
            float ov[4];
#pragma unroll
            for (int q = 0; q < 4; q++) {
                const float xi = xc[4 * j + q];
                m = st * xi + a1 * m;
                // smooth = (eps + m)^(-alpha);  exp2/log2 native
                const float smooth = fexp2(nalpha * flog2(1e-5f + m));
                // pcen = (x*smooth + delta)^r - delta^r   (arg >= delta > 0)
                ov[q] = fexp2(r * flog2(xi * smooth + delta)) - deltar;
            }
            *reinterpret_cast<float4*>(&sh[swz(tid * CHUNK + 4 * j)]) =
                make_float4(ov[0], ov[1], ov[2], ov[3]);
        }
        float* oplane = out + (((size_t)b * 4 + t) * NB + f) * (size_t)NT;
#pragma unroll
        for (int k = 0; k < 4; k++) {
            const int n = wbase + k * 256 + lane * 4;
            float4 o = *reinterpret_cast<const float4*>(&sh[swz(n)]);
            *reinterpret_cast<float4*>(oplane + n) = o;
        }
    }
}

extern "C" void kernel_launch(void* const* d_in, const int* in_sizes, int n_in,
                              void* d_out, int out_size, void* d_ws, size_t ws_size,
                              hipStream_t stream) {
    const float* x         = (const float*)d_in[0];
    const float* log_alpha = (const float*)d_in[1];
    const float* log_delta = (const float*)d_in[2];
    const float* log_r     = (const float*)d_in[3];
    float* out = (float*)d_out;

    // one block per (b, f) row: 8 * 128 = 1024 blocks, all 4 rates fused
    mrpcen_kernel<<<dim3(8 * NB), dim3(TPB), 0, stream>>>(
        x, log_alpha, log_delta, log_r, out);
}